// Round 8
// baseline (844.547 us; speedup 1.0000x reference)
//
#include <hip/hip_runtime.h>

#define H_ 256
#define M_ 256
#define L_ 4096
#define B_ 16
#define PI_F 3.14159265358979323846f

typedef unsigned short u16;
typedef __attribute__((ext_vector_type(8))) short short8v;   // 8 bf16 in 4 VGPRs
typedef __attribute__((ext_vector_type(4))) float floatx4;

__device__ __forceinline__ float sigm(float x) { return 1.0f / (1.0f + expf(-x)); }
__device__ __forceinline__ u16 f2bf(float f) {
    unsigned int u = __float_as_uint(f);
    unsigned int r = (u + 0x7fff + ((u >> 16) & 1)) >> 16;
    return (u16)r;
}
__device__ __forceinline__ float bf2f(u16 h) { return __uint_as_float(((unsigned int)h) << 16); }
__device__ __forceinline__ void split2(float x, u16& h, u16& l) {
    h = f2bf(x);
    l = f2bf(x - bf2f(h));
}

// ---------------- prep: pack weights, per-m constants ----------------
// W1h planes: [enc_hi | Bre | Bim], W1l: [enc_lo]
// W2h planes: [Wr_hi | Wt_hi | Wg], W2l: [Wr_lo | Wt_lo]
__global__ __launch_bounds__(256) void k_prep(const float* __restrict__ Bp,
                                              const float* __restrict__ Cp,
                                              const float* __restrict__ enc_w,
                                              const float* __restrict__ Wr,
                                              const float* __restrict__ Wt,
                                              const float* __restrict__ Wg,
                                              const float* __restrict__ dtb,
                                              u16* __restrict__ W1h, u16* __restrict__ W1l,
                                              u16* __restrict__ W2h, u16* __restrict__ W2l,
                                              u16* __restrict__ Chath,
                                              float* __restrict__ dtc, float* __restrict__ idt,
                                              float* __restrict__ idt2) {
    int tid = blockIdx.x * 256 + threadIdx.x;  // 0..65535
    if (tid < M_) {
        float d = fmaxf(sigm(dtb[tid]), 1e-6f);
        dtc[tid] = d;
        idt[tid] = 1.0f / d;
        idt2[tid] = 1.0f / (d * d);
    }
    u16 h, l;
    split2(enc_w[tid], h, l); W1h[tid] = h; W1l[tid] = l;
    W1h[65536 + tid]  = f2bf(Bp[2 * tid + 0]);
    W1h[131072 + tid] = f2bf(Bp[2 * tid + 1]);
    split2(Wr[tid], h, l); W2h[tid] = h; W2l[tid] = l;
    split2(Wt[tid], h, l); W2h[65536 + tid] = h; W2l[65536 + tid] = l;
    W2h[131072 + tid] = f2bf(Wg[tid]);
    int hh = tid >> 8, m = tid & (M_ - 1);
    Chath[hh * 512 + 2 * m + 0] = f2bf(Cp[2 * tid + 0]);
    Chath[hh * 512 + 2 * m + 1] = f2bf(-Cp[2 * tid + 1]);
}

__global__ __launch_bounds__(256) void k_zero(float* __restrict__ p, int n) {
    int i = blockIdx.x * 256 + threadIdx.x;
    if (i < n) p[i] = 0.0f;
}

// ---------------- fused multi-head MFMA GEMM ----------------
// NH heads of 256 cols each; first NSPLIT heads use split-bf16 (3 products).
// A: fp32 (split on the fly) if !APRE, else pre-split bf16 planes Ahi/Alo.
// EPI 1 (enc+bu): head0 -> silu+bias -> OUT1(f32); heads1,2 -> f2bf -> OUT2 planes (ungated bu)
// EPI 0 (heads+gate): heads0,1 -> (A,G) float2 OUT1; head2 -> f2bf(sigm) OUT2
template <int NH, int NSPLIT, int EPI, bool AGLOB, bool APRE>
__global__ __launch_bounds__(256) void k_fgemm(const float* __restrict__ Af,
                                               const u16* __restrict__ Ahi,
                                               const u16* __restrict__ Alo,
                                               const u16* __restrict__ Whi,
                                               const u16* __restrict__ Wlo,
                                               float* __restrict__ OUT1,
                                               u16* __restrict__ OUT2,
                                               const float* __restrict__ p0,
                                               const float* __restrict__ p1,
                                               const float* __restrict__ p2,
                                               const float* __restrict__ p3,
                                               int K, int C, int t0) {
    __shared__ u16 Ah[128][40];
    __shared__ u16 Al[128][40];
    __shared__ u16 Bh[NH][128][40];
    __shared__ u16 Bl[NSPLIT][128][40];
    const int tid = threadIdx.x;
    const int tpb = C >> 7;
    const int batch = blockIdx.y / tpb;
    const int i0 = (blockIdx.y % tpb) << 7;
    const int colBase = blockIdx.x << 7;
    const int aRow0 = AGLOB ? (batch * L_ + t0 + i0) : (batch * C + i0);
    const int oRow0 = batch * C + i0;
    const int arow = tid >> 1, aseg = (tid & 1) << 4;
    // A prefetch registers
    float4 ra0, ra1, ra2, ra3;
    short8v rah0, rah1, ral0, ral1;
    const float* paf = nullptr;
    const u16 *pah = nullptr, *pal = nullptr;
    if constexpr (APRE) {
        pah = &Ahi[(size_t)(aRow0 + arow) * K + aseg];
        pal = &Alo[(size_t)(aRow0 + arow) * K + aseg];
        rah0 = *(const short8v*)pah; rah1 = *(const short8v*)(pah + 8);
        ral0 = *(const short8v*)pal; ral1 = *(const short8v*)(pal + 8);
    } else {
        paf = &Af[(size_t)(aRow0 + arow) * K + aseg];
        ra0 = *(const float4*)paf;       ra1 = *(const float4*)(paf + 4);
        ra2 = *(const float4*)(paf + 8); ra3 = *(const float4*)(paf + 12);
    }
    const int lane = tid & 63, wv = tid >> 6;
    const int wr = wv >> 1, wc = wv & 1;
    const int fr = lane & 15, kg = lane >> 4;
    floatx4 acc[NH][4][4];
#pragma unroll
    for (int h = 0; h < NH; ++h)
#pragma unroll
        for (int i = 0; i < 4; ++i)
#pragma unroll
            for (int j = 0; j < 4; ++j) acc[h][i][j] = (floatx4){0.f, 0.f, 0.f, 0.f};
    const int KT = K >> 5;
    for (int kt = 0; kt < KT; ++kt) {
        // B regs (L2-hot weights)
        short8v rbh[NH][2], rbl[NSPLIT > 0 ? NSPLIT : 1][2];
#pragma unroll
        for (int h = 0; h < NH; ++h) {
            const u16* pb = &Whi[(size_t)h * 65536 + (size_t)(colBase + arow) * K + kt * 32 + aseg];
            rbh[h][0] = *(const short8v*)pb; rbh[h][1] = *(const short8v*)(pb + 8);
        }
#pragma unroll
        for (int h = 0; h < NSPLIT; ++h) {
            const u16* pl = &Wlo[(size_t)h * 65536 + (size_t)(colBase + arow) * K + kt * 32 + aseg];
            rbl[h][0] = *(const short8v*)pl; rbl[h][1] = *(const short8v*)(pl + 8);
        }
        __syncthreads();
        if constexpr (APRE) {
            *(short8v*)&Ah[arow][aseg] = rah0; *(short8v*)&Ah[arow][aseg + 8] = rah1;
            *(short8v*)&Al[arow][aseg] = ral0; *(short8v*)&Al[arow][aseg + 8] = ral1;
        } else {
            u16 hb[16], lb[16];
            float v[16] = {ra0.x, ra0.y, ra0.z, ra0.w, ra1.x, ra1.y, ra1.z, ra1.w,
                           ra2.x, ra2.y, ra2.z, ra2.w, ra3.x, ra3.y, ra3.z, ra3.w};
#pragma unroll
            for (int s = 0; s < 16; ++s) split2(v[s], hb[s], lb[s]);
            *(short8v*)&Ah[arow][aseg] = *(short8v*)&hb[0];
            *(short8v*)&Ah[arow][aseg + 8] = *(short8v*)&hb[8];
            *(short8v*)&Al[arow][aseg] = *(short8v*)&lb[0];
            *(short8v*)&Al[arow][aseg + 8] = *(short8v*)&lb[8];
        }
#pragma unroll
        for (int h = 0; h < NH; ++h) {
            *(short8v*)&Bh[h][arow][aseg] = rbh[h][0];
            *(short8v*)&Bh[h][arow][aseg + 8] = rbh[h][1];
        }
#pragma unroll
        for (int h = 0; h < NSPLIT; ++h) {
            *(short8v*)&Bl[h][arow][aseg] = rbl[h][0];
            *(short8v*)&Bl[h][arow][aseg + 8] = rbl[h][1];
        }
        __syncthreads();
        if (kt + 1 < KT) {
            if constexpr (APRE) {
                pah += 32; pal += 32;
                rah0 = *(const short8v*)pah; rah1 = *(const short8v*)(pah + 8);
                ral0 = *(const short8v*)pal; ral1 = *(const short8v*)(pal + 8);
            } else {
                paf += 32;
                ra0 = *(const float4*)paf;       ra1 = *(const float4*)(paf + 4);
                ra2 = *(const float4*)(paf + 8); ra3 = *(const float4*)(paf + 12);
            }
        }
        short8v afh[4], afl[4];
#pragma unroll
        for (int i = 0; i < 4; ++i) afh[i] = *(short8v*)&Ah[wr * 64 + i * 16 + fr][kg << 3];
#pragma unroll
        for (int i = 0; i < 4; ++i) afl[i] = *(short8v*)&Al[wr * 64 + i * 16 + fr][kg << 3];
#pragma unroll
        for (int h = 0; h < NH; ++h) {
            short8v bfh[4], bfl[4];
#pragma unroll
            for (int j = 0; j < 4; ++j) bfh[j] = *(short8v*)&Bh[h][wc * 64 + j * 16 + fr][kg << 3];
            if (h < NSPLIT) {
#pragma unroll
                for (int j = 0; j < 4; ++j) bfl[j] = *(short8v*)&Bl[h][wc * 64 + j * 16 + fr][kg << 3];
            }
#pragma unroll
            for (int i = 0; i < 4; ++i)
#pragma unroll
                for (int j = 0; j < 4; ++j) {
                    floatx4 t = acc[h][i][j];
                    if (h < NSPLIT) {
                        t = __builtin_amdgcn_mfma_f32_16x16x32_bf16(afl[i], bfh[j], t, 0, 0, 0);
                        t = __builtin_amdgcn_mfma_f32_16x16x32_bf16(afh[i], bfl[j], t, 0, 0, 0);
                    }
                    t = __builtin_amdgcn_mfma_f32_16x16x32_bf16(afh[i], bfh[j], t, 0, 0, 0);
                    acc[h][i][j] = t;
                }
        }
    }
    // epilogue: D[row=(lane>>4)*4+reg][col=lane&15]
#pragma unroll
    for (int i = 0; i < 4; ++i)
#pragma unroll
        for (int j = 0; j < 4; ++j) {
            int rbase = wr * 64 + i * 16 + (kg << 2);
            int col = colBase + wc * 64 + j * 16 + fr;
#pragma unroll
            for (int r = 0; r < 4; ++r) {
                int orow = oRow0 + rbase + r;
                if constexpr (EPI == 1) {
                    float v = acc[0][i][j][r] + p0[col];
                    OUT1[(size_t)orow * 256 + col] = v * sigm(v);
                    OUT2[(size_t)orow * 512 + col] = f2bf(acc[1][i][j][r]);
                    OUT2[(size_t)orow * 512 + 256 + col] = f2bf(acc[2][i][j][r]);
                } else {
                    float rr = sigm(p0[col] + acc[0][i][j][r]);
                    float th = PI_F * tanhf(p1[col] + acc[1][i][j][r]);
                    float r2 = fmaxf(rr * rr, 1e-8f);
                    float Av = fmaxf((r2 - 2.0f * rr * cosf(th) + 1.0f) * p3[col] / r2, 0.0f);
                    float Gv = fmaxf((1.0f - r2) * p2[col] / r2, 0.0f);
                    *(float2*)&OUT1[((size_t)orow * 256 + col) * 2] = make_float2(Av, Gv);
                    OUT2[(size_t)orow * 256 + col] = f2bf(sigm(acc[2][i][j][r]));
                }
            }
        }
}

// ---------------- depthwise causal conv (K=4) + SiLU -> pre-split bf16 planes ----------------
__global__ __launch_bounds__(256) void k_conv(const float* __restrict__ F0,   // (B*C,H)
                                              const float* __restrict__ TAIL, // (B,3,H)
                                              const float* __restrict__ cw,
                                              const float* __restrict__ cb,
                                              u16* __restrict__ Fhi,
                                              u16* __restrict__ Flo,
                                              int t0, int C) {
    int idx = blockIdx.x * 256 + threadIdx.x;
    int h = idx & (H_ - 1);
    int rl = idx >> 8;
    int b = rl / C;
    int dtl = rl - b * C;
    int t = t0 + dtl;
    float w0 = cw[h * 4 + 0], w1 = cw[h * 4 + 1], w2 = cw[h * 4 + 2], w3 = cw[h * 4 + 3];
    float acc = cb[h];
    acc = fmaf(F0[(size_t)rl * H_ + h], w3, acc);
#pragma unroll
    for (int kk = 1; kk <= 3; ++kk) {
        float w = (kk == 1) ? w2 : (kk == 2) ? w1 : w0;
        if (t - kk >= 0) {
            float src;
            if (dtl - kk >= 0) src = F0[(size_t)(rl - kk) * H_ + h];
            else               src = TAIL[((b * 3 + (3 + dtl - kk)) << 8) + h];
            acc = fmaf(src, w, acc);
        }
    }
    float y = acc * sigm(acc);
    u16 hh, ll;
    split2(y, hh, ll);
    Fhi[(size_t)rl * H_ + h] = hh;
    Flo[(size_t)rl * H_ + h] = ll;
}

__global__ __launch_bounds__(256) void k_tail(const float* __restrict__ F0,
                                              float* __restrict__ TAIL, int C) {
    int b = blockIdx.x / 3, j = blockIdx.x % 3, h = threadIdx.x;
    TAIL[((b * 3 + j) << 8) + h] = F0[((size_t)(b * C + C - 3 + j) << 8) + h];
}

// ---------------- parallel scan pass 1 ----------------
#define SEG_ 64
__global__ __launch_bounds__(256) void k_scan1(const float* __restrict__ AGf2,
                                               const u16* __restrict__ BUh,
                                               const u16* __restrict__ GTh,
                                               const float* __restrict__ dtc_,
                                               float* __restrict__ SEGM,
                                               float* __restrict__ SEGV,
                                               int C) {
    int m = threadIdx.x;
    int nseg = C >> 6;
    int b = blockIdx.x / nseg;
    int s = blockIdx.x - b * nseg;
    float dt = dtc_[m];
    size_t row0 = (size_t)b * C + s * SEG_;
    float a = 1.f, bb = 0.f, c = 0.f, d = 1.f;
    float vzr = 0.f, vzi = 0.f, vxr = 0.f, vxi = 0.f;
    for (int t = 0; t < SEG_; ++t) {
        size_t row = row0 + t;
        float2 ag = *(const float2*)&AGf2[(row * 256 + m) * 2];
        float g = bf2f(GTh[row * 256 + m]);
        float br = bf2f(BUh[row * 512 + m]) * g;
        float bi = bf2f(BUh[row * 512 + 256 + m]) * g;
        float S = fmaf(dt, ag.y, 1.0f);
        float e = 1.0f / fmaxf(S, 1e-6f);
        float sa = e;
        float sb = -dt * ag.x * e;
        float sc = dt * e;
        float sd = fmaf(dt, sb, 1.0f);
        float na = fmaf(sa, a, sb * c), nb = fmaf(sa, bb, sb * d);
        float nc = fmaf(sc, a, sd * c), nd = fmaf(sc, bb, sd * d);
        float wz = dt * e;
        float nvzr = fmaf(sa, vzr, fmaf(sb, vxr, wz * br));
        float nvzi = fmaf(sa, vzi, fmaf(sb, vxi, wz * bi));
        float nvxr = fmaf(sc, vzr, fmaf(sd, vxr, dt * wz * br));
        float nvxi = fmaf(sc, vzi, fmaf(sd, vxi, dt * wz * bi));
        a = na; bb = nb; c = nc; d = nd;
        vzr = nvzr; vzi = nvzi; vxr = nvxr; vxi = nvxi;
    }
    size_t o = ((size_t)blockIdx.x * M_ + m) * 4;
    *(float4*)&SEGM[o] = make_float4(a, bb, c, d);
    *(float4*)&SEGV[o] = make_float4(vzr, vzi, vxr, vxi);
}

// ---------------- scan pass 2 ----------------
__global__ __launch_bounds__(256) void k_scan2(const float* __restrict__ SEGM,
                                               const float* __restrict__ SEGV,
                                               float* __restrict__ carry,
                                               float* __restrict__ PRE,
                                               int C) {
    int m = threadIdx.x;
    int b = blockIdx.x;
    int nseg = C >> 6;
    float4 st = *(float4*)&carry[(size_t)(b * M_ + m) * 4];
    for (int s = 0; s < nseg; ++s) {
        size_t o = ((size_t)(b * nseg + s) * M_ + m) * 4;
        *(float4*)&PRE[o] = st;
        float4 Mm = *(const float4*)&SEGM[o];
        float4 Vv = *(const float4*)&SEGV[o];
        float nzr = fmaf(Mm.x, st.x, fmaf(Mm.y, st.z, Vv.x));
        float nzi = fmaf(Mm.x, st.y, fmaf(Mm.y, st.w, Vv.y));
        float nxr = fmaf(Mm.z, st.x, fmaf(Mm.w, st.z, Vv.z));
        float nxi = fmaf(Mm.z, st.y, fmaf(Mm.w, st.w, Vv.w));
        st = make_float4(nzr, nzi, nxr, nxi);
    }
    *(float4*)&carry[(size_t)(b * M_ + m) * 4] = st;
}

// ---------------- scan pass 3 fused with projection GEMM + D*x residual ----------------
__global__ __launch_bounds__(256) void k_scan3p(const float* __restrict__ AGf2,
                                                const u16* __restrict__ BUh,
                                                const u16* __restrict__ GTh,
                                                const float* __restrict__ dtc_,
                                                const float* __restrict__ PRE,
                                                const u16* __restrict__ Chath,  // (256,512)
                                                const float* __restrict__ Dv,
                                                const float* __restrict__ X0,
                                                float* __restrict__ OUT,
                                                int t0, int C) {
    __shared__ u16 XT[32][520];
    __shared__ u16 Bs[256][40];
    const int tid = threadIdx.x;
    const int m = tid;
    const int nseg = C >> 6;
    const int b = blockIdx.x / nseg;
    const int s = blockIdx.x - b * nseg;
    const float dt = dtc_[m];
    float4 st = *(const float4*)&PRE[((size_t)blockIdx.x * M_ + m) * 4];
    float zr = st.x, zi = st.y, xr = st.z, xi = st.w;
    const size_t row0 = (size_t)b * C + s * SEG_;
    const int grow0 = b * L_ + t0 + s * SEG_;
    const int lane = tid & 63, wc = tid >> 6;
    const int fr = lane & 15, kg = lane >> 4;
#pragma unroll
    for (int half = 0; half < 2; ++half) {
        for (int t = 0; t < 32; ++t) {
            size_t row = row0 + half * 32 + t;
            float2 ag = *(const float2*)&AGf2[(row * 256 + m) * 2];
            float g = bf2f(GTh[row * 256 + m]);
            float br = bf2f(BUh[row * 512 + m]) * g;
            float bi = bf2f(BUh[row * 512 + 256 + m]) * g;
            float S = fmaf(dt, ag.y, 1.0f);
            float inv = 1.0f / fmaxf(S, 1e-6f);
            zr = fmaf(dt, fmaf(-ag.x, xr, br), zr) * inv;
            zi = fmaf(dt, fmaf(-ag.x, xi, bi), zi) * inv;
            xr = fmaf(dt, zr, xr);
            xi = fmaf(dt, zi, xi);
            unsigned int pk = (unsigned int)f2bf(xr) | ((unsigned int)f2bf(xi) << 16);
            *(unsigned int*)&XT[t][2 * m] = pk;
        }
        __syncthreads();
        floatx4 pacc[2][4];
#pragma unroll
        for (int i = 0; i < 2; ++i)
#pragma unroll
            for (int j = 0; j < 4; ++j) pacc[i][j] = (floatx4){0.f, 0.f, 0.f, 0.f};
        for (int kc = 0; kc < 16; ++kc) {
            const u16* pc = &Chath[(size_t)tid * 512 + kc * 32];
            short8v c0 = *(const short8v*)pc;
            short8v c1 = *(const short8v*)(pc + 8);
            short8v c2 = *(const short8v*)(pc + 16);
            short8v c3 = *(const short8v*)(pc + 24);
            *(short8v*)&Bs[tid][0]  = c0;
            *(short8v*)&Bs[tid][8]  = c1;
            *(short8v*)&Bs[tid][16] = c2;
            *(short8v*)&Bs[tid][24] = c3;
            __syncthreads();
            short8v af[2], bf[4];
#pragma unroll
            for (int i = 0; i < 2; ++i) af[i] = *(short8v*)&XT[i * 16 + fr][kc * 32 + (kg << 3)];
#pragma unroll
            for (int j = 0; j < 4; ++j) bf[j] = *(short8v*)&Bs[wc * 64 + j * 16 + fr][kg << 3];
#pragma unroll
            for (int i = 0; i < 2; ++i)
#pragma unroll
                for (int j = 0; j < 4; ++j)
                    pacc[i][j] = __builtin_amdgcn_mfma_f32_16x16x32_bf16(af[i], bf[j], pacc[i][j], 0, 0, 0);
            __syncthreads();
        }
#pragma unroll
        for (int i = 0; i < 2; ++i)
#pragma unroll
            for (int j = 0; j < 4; ++j) {
                int col = wc * 64 + j * 16 + fr;
#pragma unroll
                for (int r = 0; r < 4; ++r) {
                    int grow = grow0 + half * 32 + i * 16 + (kg << 2) + r;
                    OUT[(size_t)grow * 256 + col] =
                        fmaf(Dv[col], X0[(size_t)grow * 256 + col], pacc[i][j][r]);
                }
            }
        __syncthreads();
    }
}

extern "C" void kernel_launch(void* const* d_in, const int* in_sizes, int n_in,
                              void* d_out, int out_size, void* d_ws, size_t ws_size,
                              hipStream_t stream) {
    const float* inputs = (const float*)d_in[0];
    const float* Bp     = (const float*)d_in[1];
    const float* Cp     = (const float*)d_in[2];
    const float* Dv     = (const float*)d_in[3];
    const float* enc_w  = (const float*)d_in[4];
    const float* enc_b  = (const float*)d_in[5];
    const float* conv_w = (const float*)d_in[6];
    const float* conv_b = (const float*)d_in[7];
    const float* rlb    = (const float*)d_in[8];
    const float* tab    = (const float*)d_in[9];
    const float* Wr     = (const float*)d_in[10];
    const float* Wt     = (const float*)d_in[11];
    const float* dtb    = (const float*)d_in[12];
    const float* Wg     = (const float*)d_in[13];

    int C = 4096;
    while (C > 128) {
        size_t need = (size_t)B_ * C * 5632 + (48ull << 20);
        if (need <= ws_size) break;
        C >>= 1;
    }

    char* ws = (char*)d_ws;
    size_t off = 0;
    auto alloc = [&](size_t bytes) -> char* {
        char* p = ws + off;
        off = (off + bytes + 1023) & ~(size_t)1023;
        return p;
    };
    const int rows = B_ * C;
    const int nseg = C >> 6;
    float* F0   = (float*)alloc((size_t)rows * 256 * 4);
    u16*   Fhi  = (u16*)alloc((size_t)rows * 256 * 2);
    u16*   Flo  = (u16*)alloc((size_t)rows * 256 * 2);
    float* AGf2 = (float*)alloc((size_t)rows * 512 * 4);
    u16*   GTh  = (u16*)alloc((size_t)rows * 256 * 2);
    u16*   BUh  = (u16*)alloc((size_t)rows * 512 * 2);
    float* SEGM = (float*)alloc((size_t)B_ * nseg * M_ * 16);
    float* SEGV = (float*)alloc((size_t)B_ * nseg * M_ * 16);
    float* PRE  = (float*)alloc((size_t)B_ * nseg * M_ * 16);
    u16* W1h  = (u16*)alloc(3 * 65536 * 2);
    u16* W1l  = (u16*)alloc(1 * 65536 * 2);
    u16* W2h  = (u16*)alloc(3 * 65536 * 2);
    u16* W2l  = (u16*)alloc(2 * 65536 * 2);
    u16* Chath= (u16*)alloc(2 * 65536 * 2);
    float* dtc  = (float*)alloc(1024);
    float* idt  = (float*)alloc(1024);
    float* idt2 = (float*)alloc(1024);
    float* carry= (float*)alloc(B_ * M_ * 16);
    float* TAIL = (float*)alloc(B_ * 3 * 256 * 4);

    const int NC = L_ / C;
    const int tpb = C >> 7;

    k_prep<<<256, 256, 0, stream>>>(Bp, Cp, enc_w, Wr, Wt, Wg, dtb,
                                    W1h, W1l, W2h, W2l, Chath, dtc, idt, idt2);
    k_zero<<<(B_ * M_ * 4 + 255) / 256, 256, 0, stream>>>(carry, B_ * M_ * 4);

    for (int c = 0; c < NC; ++c) {
        int t0 = c * C;
        // enc + bu: head0 = enc (split), heads1,2 = Bre,Bim (plain) -> F0 + ungated BUh
        k_fgemm<3, 1, 1, true, false><<<dim3(2, B_ * tpb), 256, 0, stream>>>(
            inputs, nullptr, nullptr, W1h, W1l, F0, BUh,
            enc_b, nullptr, nullptr, nullptr, 256, C, t0);
        k_conv<<<rows, 256, 0, stream>>>(F0, TAIL, conv_w, conv_b, Fhi, Flo, t0, C);
        k_tail<<<B_ * 3, 256, 0, stream>>>(F0, TAIL, C);
        // heads + gate: heads0,1 = r,theta (split), head2 = gate (plain) -> AGf2 + GTh
        k_fgemm<3, 2, 0, false, true><<<dim3(2, B_ * tpb), 256, 0, stream>>>(
            nullptr, Fhi, Flo, W2h, W2l, AGf2, GTh,
            rlb, tab, idt, idt2, 256, C, t0);
        k_scan1<<<B_ * nseg, 256, 0, stream>>>(AGf2, BUh, GTh, dtc, SEGM, SEGV, C);
        k_scan2<<<B_, 256, 0, stream>>>(SEGM, SEGV, carry, PRE, C);
        k_scan3p<<<B_ * nseg, 256, 0, stream>>>(AGf2, BUh, GTh, dtc, PRE, Chath, Dv, inputs,
                                                (float*)d_out, t0, C);
    }
}

// Round 9
// 838.866 us; speedup vs baseline: 1.0068x; 1.0068x over previous
//
#include <hip/hip_runtime.h>

#define H_ 256
#define M_ 256
#define L_ 4096
#define B_ 16
#define PI_F 3.14159265358979323846f

typedef unsigned short u16;
typedef __attribute__((ext_vector_type(8))) short short8v;   // 8 bf16 in 4 VGPRs
typedef __attribute__((ext_vector_type(4))) float floatx4;

__device__ __forceinline__ float sigm(float x) { return 1.0f / (1.0f + expf(-x)); }
__device__ __forceinline__ u16 f2bf(float f) {
    unsigned int u = __float_as_uint(f);
    unsigned int r = (u + 0x7fff + ((u >> 16) & 1)) >> 16;
    return (u16)r;
}
__device__ __forceinline__ float bf2f(u16 h) { return __uint_as_float(((unsigned int)h) << 16); }
__device__ __forceinline__ void split2(float x, u16& h, u16& l) {
    h = f2bf(x);
    l = f2bf(x - bf2f(h));
}

// ---------------- prep: split/pack weights, per-m constants ----------------
__global__ __launch_bounds__(256) void k_prep(const float* __restrict__ Bp,   // (M,H,2)
                                              const float* __restrict__ Cp,   // (H,M,2)
                                              const float* __restrict__ enc_w,
                                              const float* __restrict__ Wr,
                                              const float* __restrict__ Wt,
                                              const float* __restrict__ Wg,
                                              const float* __restrict__ dtb,
                                              u16* __restrict__ EWhi, u16* __restrict__ EWlo,
                                              u16* __restrict__ HWhi, u16* __restrict__ HWlo, // r, theta
                                              u16* __restrict__ GWhi,
                                              u16* __restrict__ WBh,     // (512,256): Bre rows, Bim rows
                                              u16* __restrict__ Chath,   // (256,512): [h][2m]=Cre,[h][2m+1]=-Cim
                                              float* __restrict__ dtc, float* __restrict__ idt,
                                              float* __restrict__ idt2) {
    int tid = blockIdx.x * 256 + threadIdx.x;  // 0..65535
    if (tid < M_) {
        float d = fmaxf(sigm(dtb[tid]), 1e-6f);
        dtc[tid] = d;
        idt[tid] = 1.0f / d;
        idt2[tid] = 1.0f / (d * d);
    }
    u16 h, l;
    split2(enc_w[tid], h, l); EWhi[tid] = h; EWlo[tid] = l;
    split2(Wr[tid], h, l);    HWhi[tid] = h; HWlo[tid] = l;
    split2(Wt[tid], h, l);    HWhi[65536 + tid] = h; HWlo[65536 + tid] = l;
    GWhi[tid] = f2bf(Wg[tid]);
    WBh[tid]         = f2bf(Bp[2 * tid + 0]);
    WBh[65536 + tid] = f2bf(Bp[2 * tid + 1]);
    int hh = tid >> 8, m = tid & (M_ - 1);
    Chath[hh * 512 + 2 * m + 0] = f2bf(Cp[2 * tid + 0]);
    Chath[hh * 512 + 2 * m + 1] = f2bf(-Cp[2 * tid + 1]);
}

__global__ __launch_bounds__(256) void k_zero(float* __restrict__ p, int n) {
    int i = blockIdx.x * 256 + threadIdx.x;
    if (i < n) p[i] = 0.0f;
}

// ---------------- split-bf16 MFMA GEMM over fp32 A ----------------
// OUT = A(rows,K) @ W[h](256,K)^T per head. NPROD=3: hi*hi+hi*lo+lo*hi; NPROD=1: hi*hi.
// EPI: 1=enc silu+bias (f32 OUT) | 0=heads r,theta -> (A,G) float2 | 2=gate sigm -> bf16
//      3=bu (NH=2) -> bf16 planes gated by g16
template <int NH, int NPROD, int EPI, bool AGLOB>
__global__ __launch_bounds__(256) void k_sgemm(const float* __restrict__ A,
                                               const u16* __restrict__ Whi,
                                               const u16* __restrict__ Wlo,
                                               void* __restrict__ OUTv,
                                               const u16* __restrict__ g16,
                                               const float* __restrict__ p0,  // bias | rlb
                                               const float* __restrict__ p1,  // tab
                                               const float* __restrict__ p2,  // idt
                                               const float* __restrict__ p3,  // idt2
                                               int K, int C, int t0) {
    constexpr int LOR = (NPROD == 3) ? 128 : 1;
    constexpr int NBL = (NPROD == 3) ? NH : 1;
    __shared__ u16 Ah[128][40];
    __shared__ u16 Al[LOR][40];
    __shared__ u16 Bh[NH][128][40];
    __shared__ u16 Bl[NBL][LOR][40];
    const int tid = threadIdx.x;
    const int tpb = C >> 7;
    const int batch = blockIdx.y / tpb;
    const int i0 = (blockIdx.y % tpb) << 7;
    const int colBase = blockIdx.x << 7;
    const int aRow0 = AGLOB ? (batch * L_ + t0 + i0) : (batch * C + i0);
    const int oRow0 = batch * C + i0;
    const int arow = tid >> 1, aseg = (tid & 1) << 4;
    const float* pa = &A[(size_t)(aRow0 + arow) * K + aseg];
    float4 ra0 = *(const float4*)pa, ra1 = *(const float4*)(pa + 4);
    float4 ra2 = *(const float4*)(pa + 8), ra3 = *(const float4*)(pa + 12);
    const int lane = tid & 63, wv = tid >> 6;
    const int wr = wv >> 1, wc = wv & 1;
    const int fr = lane & 15, kg = lane >> 4;
    floatx4 acc[NH][4][4];
#pragma unroll
    for (int h = 0; h < NH; ++h)
#pragma unroll
        for (int i = 0; i < 4; ++i)
#pragma unroll
            for (int j = 0; j < 4; ++j) acc[h][i][j] = (floatx4){0.f, 0.f, 0.f, 0.f};
    const int KT = K >> 5;
    for (int kt = 0; kt < KT; ++kt) {
        short8v rbh[NH][2], rbl[NBL][2];
#pragma unroll
        for (int h = 0; h < NH; ++h) {
            const u16* pb = &Whi[(size_t)h * 65536 + (size_t)(colBase + arow) * K + kt * 32 + aseg];
            rbh[h][0] = *(const short8v*)pb; rbh[h][1] = *(const short8v*)(pb + 8);
            if (NPROD == 3) {
                const u16* pl = &Wlo[(size_t)h * 65536 + (size_t)(colBase + arow) * K + kt * 32 + aseg];
                rbl[h][0] = *(const short8v*)pl; rbl[h][1] = *(const short8v*)(pl + 8);
            }
        }
        __syncthreads();
        {
            u16 hb[16], lb[16];
            float v[16] = {ra0.x, ra0.y, ra0.z, ra0.w, ra1.x, ra1.y, ra1.z, ra1.w,
                           ra2.x, ra2.y, ra2.z, ra2.w, ra3.x, ra3.y, ra3.z, ra3.w};
#pragma unroll
            for (int s = 0; s < 16; ++s) {
                if (NPROD == 3) split2(v[s], hb[s], lb[s]);
                else hb[s] = f2bf(v[s]);
            }
            *(short8v*)&Ah[arow][aseg] = *(short8v*)&hb[0];
            *(short8v*)&Ah[arow][aseg + 8] = *(short8v*)&hb[8];
            if (NPROD == 3) {
                *(short8v*)&Al[arow][aseg] = *(short8v*)&lb[0];
                *(short8v*)&Al[arow][aseg + 8] = *(short8v*)&lb[8];
            }
        }
#pragma unroll
        for (int h = 0; h < NH; ++h) {
            *(short8v*)&Bh[h][arow][aseg] = rbh[h][0];
            *(short8v*)&Bh[h][arow][aseg + 8] = rbh[h][1];
            if (NPROD == 3) {
                *(short8v*)&Bl[h][arow][aseg] = rbl[h][0];
                *(short8v*)&Bl[h][arow][aseg + 8] = rbl[h][1];
            }
        }
        __syncthreads();
        if (kt + 1 < KT) {
            pa += 32;
            ra0 = *(const float4*)pa; ra1 = *(const float4*)(pa + 4);
            ra2 = *(const float4*)(pa + 8); ra3 = *(const float4*)(pa + 12);
        }
        short8v afh[4], afl[4];
#pragma unroll
        for (int i = 0; i < 4; ++i) afh[i] = *(short8v*)&Ah[wr * 64 + i * 16 + fr][kg << 3];
        if (NPROD == 3) {
#pragma unroll
            for (int i = 0; i < 4; ++i) afl[i] = *(short8v*)&Al[wr * 64 + i * 16 + fr][kg << 3];
        }
#pragma unroll
        for (int h = 0; h < NH; ++h) {
            short8v bfh[4], bfl[4];
#pragma unroll
            for (int j = 0; j < 4; ++j) bfh[j] = *(short8v*)&Bh[h][wc * 64 + j * 16 + fr][kg << 3];
            if (h < NBL && NPROD == 3) {
#pragma unroll
                for (int j = 0; j < 4; ++j) bfl[j] = *(short8v*)&Bl[h][wc * 64 + j * 16 + fr][kg << 3];
            }
#pragma unroll
            for (int i = 0; i < 4; ++i)
#pragma unroll
                for (int j = 0; j < 4; ++j) {
                    floatx4 t = acc[h][i][j];
                    if (NPROD == 3) {
                        t = __builtin_amdgcn_mfma_f32_16x16x32_bf16(afl[i], bfh[j], t, 0, 0, 0);
                        t = __builtin_amdgcn_mfma_f32_16x16x32_bf16(afh[i], bfl[j], t, 0, 0, 0);
                    }
                    t = __builtin_amdgcn_mfma_f32_16x16x32_bf16(afh[i], bfh[j], t, 0, 0, 0);
                    acc[h][i][j] = t;
                }
        }
    }
    // epilogue: D[row=(lane>>4)*4+reg][col=lane&15]
#pragma unroll
    for (int i = 0; i < 4; ++i)
#pragma unroll
        for (int j = 0; j < 4; ++j) {
            int rbase = wr * 64 + i * 16 + (kg << 2);
            int col = colBase + wc * 64 + j * 16 + fr;
#pragma unroll
            for (int r = 0; r < 4; ++r) {
                int orow = oRow0 + rbase + r;
                if (EPI == 1) {
                    float v = acc[0][i][j][r] + p0[col];
                    ((float*)OUTv)[(size_t)orow * 256 + col] = v * sigm(v);
                } else if (EPI == 2) {
                    ((u16*)OUTv)[(size_t)orow * 256 + col] = f2bf(sigm(acc[0][i][j][r]));
                } else if (EPI == 0) {
                    float rr = sigm(p0[col] + acc[0][i][j][r]);
                    float th = PI_F * tanhf(p1[col] + acc[1][i][j][r]);
                    float r2 = fmaxf(rr * rr, 1e-8f);
                    float Av = fmaxf((r2 - 2.0f * rr * cosf(th) + 1.0f) * p3[col] / r2, 0.0f);
                    float Gv = fmaxf((1.0f - r2) * p2[col] / r2, 0.0f);
                    *(float2*)&((float*)OUTv)[((size_t)orow * 256 + col) * 2] = make_float2(Av, Gv);
                } else {  // EPI==3: bu, NH=2 planes, gated
                    float g = bf2f(g16[(size_t)orow * 256 + col]);
#pragma unroll
                    for (int h = 0; h < NH; ++h)
                        ((u16*)OUTv)[(size_t)orow * 512 + h * 256 + col] = f2bf(acc[h][i][j][r] * g);
                }
            }
        }
}

// ---------------- depthwise causal conv (K=4) + SiLU ----------------
__global__ __launch_bounds__(256) void k_conv(const float* __restrict__ F0,   // (B*C,H)
                                              const float* __restrict__ TAIL, // (B,3,H)
                                              const float* __restrict__ cw,
                                              const float* __restrict__ cb,
                                              float* __restrict__ F,
                                              int t0, int C) {
    int idx = blockIdx.x * 256 + threadIdx.x;
    int h = idx & (H_ - 1);
    int rl = idx >> 8;
    int b = rl / C;
    int dtl = rl - b * C;
    int t = t0 + dtl;
    float w0 = cw[h * 4 + 0], w1 = cw[h * 4 + 1], w2 = cw[h * 4 + 2], w3 = cw[h * 4 + 3];
    float acc = cb[h];
    acc = fmaf(F0[(size_t)rl * H_ + h], w3, acc);
#pragma unroll
    for (int kk = 1; kk <= 3; ++kk) {
        float w = (kk == 1) ? w2 : (kk == 2) ? w1 : w0;
        if (t - kk >= 0) {
            float src;
            if (dtl - kk >= 0) src = F0[(size_t)(rl - kk) * H_ + h];
            else               src = TAIL[((b * 3 + (3 + dtl - kk)) << 8) + h];
            acc = fmaf(src, w, acc);
        }
    }
    F[(size_t)rl * H_ + h] = acc * sigm(acc);
}

__global__ __launch_bounds__(256) void k_tail(const float* __restrict__ F0,
                                              float* __restrict__ TAIL, int C) {
    int b = blockIdx.x / 3, j = blockIdx.x % 3, h = threadIdx.x;
    TAIL[((b * 3 + j) << 8) + h] = F0[((size_t)(b * C + C - 3 + j) << 8) + h];
}

// ---------------- parallel scan pass 1 ----------------
#define SEG_ 64
__global__ __launch_bounds__(256) void k_scan1(const float* __restrict__ AGf2,
                                               const u16* __restrict__ BUh,
                                               const float* __restrict__ dtc_,
                                               float* __restrict__ SEGM,
                                               float* __restrict__ SEGV,
                                               int C) {
    int m = threadIdx.x;
    int nseg = C >> 6;
    int b = blockIdx.x / nseg;
    int s = blockIdx.x - b * nseg;
    float dt = dtc_[m];
    size_t row0 = (size_t)b * C + s * SEG_;
    float a = 1.f, bb = 0.f, c = 0.f, d = 1.f;
    float vzr = 0.f, vzi = 0.f, vxr = 0.f, vxi = 0.f;
    for (int t = 0; t < SEG_; ++t) {
        size_t row = row0 + t;
        float2 ag = *(const float2*)&AGf2[(row * 256 + m) * 2];
        float br = bf2f(BUh[row * 512 + m]);
        float bi = bf2f(BUh[row * 512 + 256 + m]);
        float S = fmaf(dt, ag.y, 1.0f);
        float e = 1.0f / fmaxf(S, 1e-6f);
        float sa = e;
        float sb = -dt * ag.x * e;
        float sc = dt * e;
        float sd = fmaf(dt, sb, 1.0f);
        float na = fmaf(sa, a, sb * c), nb = fmaf(sa, bb, sb * d);
        float nc = fmaf(sc, a, sd * c), nd = fmaf(sc, bb, sd * d);
        float wz = dt * e;
        float nvzr = fmaf(sa, vzr, fmaf(sb, vxr, wz * br));
        float nvzi = fmaf(sa, vzi, fmaf(sb, vxi, wz * bi));
        float nvxr = fmaf(sc, vzr, fmaf(sd, vxr, dt * wz * br));
        float nvxi = fmaf(sc, vzi, fmaf(sd, vxi, dt * wz * bi));
        a = na; bb = nb; c = nc; d = nd;
        vzr = nvzr; vzi = nvzi; vxr = nvxr; vxi = nvxi;
    }
    size_t o = ((size_t)blockIdx.x * M_ + m) * 4;
    *(float4*)&SEGM[o] = make_float4(a, bb, c, d);
    *(float4*)&SEGV[o] = make_float4(vzr, vzi, vxr, vxi);
}

// ---------------- scan pass 2 ----------------
__global__ __launch_bounds__(256) void k_scan2(const float* __restrict__ SEGM,
                                               const float* __restrict__ SEGV,
                                               float* __restrict__ carry,
                                               float* __restrict__ PRE,
                                               int C) {
    int m = threadIdx.x;
    int b = blockIdx.x;
    int nseg = C >> 6;
    float4 st = *(float4*)&carry[(size_t)(b * M_ + m) * 4];
    for (int s = 0; s < nseg; ++s) {
        size_t o = ((size_t)(b * nseg + s) * M_ + m) * 4;
        *(float4*)&PRE[o] = st;
        float4 Mm = *(const float4*)&SEGM[o];
        float4 Vv = *(const float4*)&SEGV[o];
        float nzr = fmaf(Mm.x, st.x, fmaf(Mm.y, st.z, Vv.x));
        float nzi = fmaf(Mm.x, st.y, fmaf(Mm.y, st.w, Vv.y));
        float nxr = fmaf(Mm.z, st.x, fmaf(Mm.w, st.z, Vv.z));
        float nxi = fmaf(Mm.z, st.y, fmaf(Mm.w, st.w, Vv.w));
        st = make_float4(nzr, nzi, nxr, nxi);
    }
    *(float4*)&carry[(size_t)(b * M_ + m) * 4] = st;
}

// ---------------- scan pass 3 fused with projection GEMM + D*x residual ----------------
__global__ __launch_bounds__(256) void k_scan3p(const float* __restrict__ AGf2,
                                                const u16* __restrict__ BUh,
                                                const float* __restrict__ dtc_,
                                                const float* __restrict__ PRE,
                                                const u16* __restrict__ Chath,  // (256,512)
                                                const float* __restrict__ Dv,
                                                const float* __restrict__ X0,   // inputs (global rows)
                                                float* __restrict__ OUT,        // (global rows)
                                                int t0, int C) {
    __shared__ u16 XT[32][520];
    __shared__ u16 Bs[256][40];
    const int tid = threadIdx.x;
    const int m = tid;
    const int nseg = C >> 6;
    const int b = blockIdx.x / nseg;
    const int s = blockIdx.x - b * nseg;
    const float dt = dtc_[m];
    float4 st = *(const float4*)&PRE[((size_t)blockIdx.x * M_ + m) * 4];
    float zr = st.x, zi = st.y, xr = st.z, xi = st.w;
    const size_t row0 = (size_t)b * C + s * SEG_;
    const int grow0 = b * L_ + t0 + s * SEG_;
    const int lane = tid & 63, wc = tid >> 6;
    const int fr = lane & 15, kg = lane >> 4;
#pragma unroll
    for (int half = 0; half < 2; ++half) {
        for (int t = 0; t < 32; ++t) {
            size_t row = row0 + half * 32 + t;
            float2 ag = *(const float2*)&AGf2[(row * 256 + m) * 2];
            float br = bf2f(BUh[row * 512 + m]);
            float bi = bf2f(BUh[row * 512 + 256 + m]);
            float S = fmaf(dt, ag.y, 1.0f);
            float inv = 1.0f / fmaxf(S, 1e-6f);
            zr = fmaf(dt, fmaf(-ag.x, xr, br), zr) * inv;
            zi = fmaf(dt, fmaf(-ag.x, xi, bi), zi) * inv;
            xr = fmaf(dt, zr, xr);
            xi = fmaf(dt, zi, xi);
            unsigned int pk = (unsigned int)f2bf(xr) | ((unsigned int)f2bf(xi) << 16);
            *(unsigned int*)&XT[t][2 * m] = pk;
        }
        __syncthreads();
        floatx4 pacc[2][4];
#pragma unroll
        for (int i = 0; i < 2; ++i)
#pragma unroll
            for (int j = 0; j < 4; ++j) pacc[i][j] = (floatx4){0.f, 0.f, 0.f, 0.f};
        for (int kc = 0; kc < 16; ++kc) {
            const u16* pc = &Chath[(size_t)tid * 512 + kc * 32];
            short8v c0 = *(const short8v*)pc;
            short8v c1 = *(const short8v*)(pc + 8);
            short8v c2 = *(const short8v*)(pc + 16);
            short8v c3 = *(const short8v*)(pc + 24);
            *(short8v*)&Bs[tid][0]  = c0;
            *(short8v*)&Bs[tid][8]  = c1;
            *(short8v*)&Bs[tid][16] = c2;
            *(short8v*)&Bs[tid][24] = c3;
            __syncthreads();
            short8v af[2], bf[4];
#pragma unroll
            for (int i = 0; i < 2; ++i) af[i] = *(short8v*)&XT[i * 16 + fr][kc * 32 + (kg << 3)];
#pragma unroll
            for (int j = 0; j < 4; ++j) bf[j] = *(short8v*)&Bs[wc * 64 + j * 16 + fr][kg << 3];
#pragma unroll
            for (int i = 0; i < 2; ++i)
#pragma unroll
                for (int j = 0; j < 4; ++j)
                    pacc[i][j] = __builtin_amdgcn_mfma_f32_16x16x32_bf16(af[i], bf[j], pacc[i][j], 0, 0, 0);
            __syncthreads();
        }
#pragma unroll
        for (int i = 0; i < 2; ++i)
#pragma unroll
            for (int j = 0; j < 4; ++j) {
                int col = wc * 64 + j * 16 + fr;
#pragma unroll
                for (int r = 0; r < 4; ++r) {
                    int grow = grow0 + half * 32 + i * 16 + (kg << 2) + r;
                    OUT[(size_t)grow * 256 + col] =
                        fmaf(Dv[col], X0[(size_t)grow * 256 + col], pacc[i][j][r]);
                }
            }
        __syncthreads();
    }
}

extern "C" void kernel_launch(void* const* d_in, const int* in_sizes, int n_in,
                              void* d_out, int out_size, void* d_ws, size_t ws_size,
                              hipStream_t stream) {
    const float* inputs = (const float*)d_in[0];
    const float* Bp     = (const float*)d_in[1];
    const float* Cp     = (const float*)d_in[2];
    const float* Dv     = (const float*)d_in[3];
    const float* enc_w  = (const float*)d_in[4];
    const float* enc_b  = (const float*)d_in[5];
    const float* conv_w = (const float*)d_in[6];
    const float* conv_b = (const float*)d_in[7];
    const float* rlb    = (const float*)d_in[8];
    const float* tab    = (const float*)d_in[9];
    const float* Wr     = (const float*)d_in[10];
    const float* Wt     = (const float*)d_in[11];
    const float* dtb    = (const float*)d_in[12];
    const float* Wg     = (const float*)d_in[13];

    // chunk length C capped at 1024 so the per-iteration working set (~126 MB)
    // stays resident in the 256 MB Infinity Cache -> intermediates never hit HBM
    int C = 1024;
    while (C > 128) {
        size_t need = (size_t)B_ * C * 5632 + (48ull << 20);
        if (need <= ws_size) break;
        C >>= 1;
    }

    char* ws = (char*)d_ws;
    size_t off = 0;
    auto alloc = [&](size_t bytes) -> char* {
        char* p = ws + off;
        off = (off + bytes + 1023) & ~(size_t)1023;
        return p;
    };
    const int rows = B_ * C;
    const int nseg = C >> 6;
    float* F0   = (float*)alloc((size_t)rows * 256 * 4);
    float* F    = (float*)alloc((size_t)rows * 256 * 4);
    float* AGf2 = (float*)alloc((size_t)rows * 512 * 4);
    u16*   GTh  = (u16*)alloc((size_t)rows * 256 * 2);
    u16*   BUh  = (u16*)alloc((size_t)rows * 512 * 2);
    float* SEGM = (float*)alloc((size_t)B_ * nseg * M_ * 16);
    float* SEGV = (float*)alloc((size_t)B_ * nseg * M_ * 16);
    float* PRE  = (float*)alloc((size_t)B_ * nseg * M_ * 16);
    u16* EWhi = (u16*)alloc(65536 * 2);
    u16* EWlo = (u16*)alloc(65536 * 2);
    u16* HWhi = (u16*)alloc(2 * 65536 * 2);
    u16* HWlo = (u16*)alloc(2 * 65536 * 2);
    u16* GWhi = (u16*)alloc(65536 * 2);
    u16* WBh  = (u16*)alloc(2 * 65536 * 2);
    u16* Chath= (u16*)alloc(2 * 65536 * 2);
    float* dtc  = (float*)alloc(1024);
    float* idt  = (float*)alloc(1024);
    float* idt2 = (float*)alloc(1024);
    float* carry= (float*)alloc(B_ * M_ * 16);
    float* TAIL = (float*)alloc(B_ * 3 * 256 * 4);

    const int NC = L_ / C;
    const int tpb = C >> 7;

    k_prep<<<256, 256, 0, stream>>>(Bp, Cp, enc_w, Wr, Wt, Wg, dtb,
                                    EWhi, EWlo, HWhi, HWlo, GWhi, WBh, Chath, dtc, idt, idt2);
    k_zero<<<(B_ * M_ * 4 + 255) / 256, 256, 0, stream>>>(carry, B_ * M_ * 4);

    for (int c = 0; c < NC; ++c) {
        int t0 = c * C;
        // encoder: split-bf16, silu(x@EW^T+b) -> F0
        k_sgemm<1, 3, 1, true><<<dim3(2, B_ * tpb), 256, 0, stream>>>(
            inputs, EWhi, EWlo, F0, nullptr, enc_b, nullptr, nullptr, nullptr, 256, C, t0);
        k_conv<<<rows, 256, 0, stream>>>(F0, TAIL, conv_w, conv_b, F, t0, C);
        k_tail<<<B_ * 3, 256, 0, stream>>>(F0, TAIL, C);
        // r/theta heads: split-bf16 -> (A,G) float2
        k_sgemm<2, 3, 0, false><<<dim3(2, B_ * tpb), 256, 0, stream>>>(
            F, HWhi, HWlo, AGf2, nullptr, rlb, tab, idt, idt2, 256, C, t0);
        // gate head: plain bf16 -> sigm -> bf16 GTh
        k_sgemm<1, 1, 2, false><<<dim3(2, B_ * tpb), 256, 0, stream>>>(
            F, GWhi, nullptr, GTh, nullptr, nullptr, nullptr, nullptr, nullptr, 256, C, t0);
        // bu: two heads (re,im) from fp32 inputs, gated -> bf16 BUh
        k_sgemm<2, 1, 3, true><<<dim3(2, B_ * tpb), 256, 0, stream>>>(
            inputs, WBh, nullptr, BUh, GTh, nullptr, nullptr, nullptr, nullptr, 256, C, t0);
        k_scan1<<<B_ * nseg, 256, 0, stream>>>(AGf2, BUh, dtc, SEGM, SEGV, C);
        k_scan2<<<B_, 256, 0, stream>>>(SEGM, SEGV, carry, PRE, C);
        k_scan3p<<<B_ * nseg, 256, 0, stream>>>(AGf2, BUh, dtc, PRE, Chath, Dv, inputs,
                                                (float*)d_out, t0, C);
    }
}

// Round 11
// 725.893 us; speedup vs baseline: 1.1635x; 1.1556x over previous
//
#include <hip/hip_runtime.h>

#define H_ 256
#define M_ 256
#define L_ 4096
#define B_ 16
#define PI_F 3.14159265358979323846f

typedef unsigned short u16;
typedef __attribute__((ext_vector_type(8))) short short8v;   // 8 bf16 in 4 VGPRs
typedef __attribute__((ext_vector_type(4))) float floatx4;
typedef __attribute__((ext_vector_type(2))) float floatx2;

__device__ __forceinline__ float sigm(float x) { return 1.0f / (1.0f + expf(-x)); }
__device__ __forceinline__ u16 f2bf(float f) {
    unsigned int u = __float_as_uint(f);
    unsigned int r = (u + 0x7fff + ((u >> 16) & 1)) >> 16;
    return (u16)r;
}
__device__ __forceinline__ float bf2f(u16 h) { return __uint_as_float(((unsigned int)h) << 16); }
__device__ __forceinline__ void split2(float x, u16& h, u16& l) {
    h = f2bf(x);
    l = f2bf(x - bf2f(h));
}

// ---------------- prep: split/pack weights, per-m constants ----------------
__global__ __launch_bounds__(256) void k_prep(const float* __restrict__ Bp,   // (M,H,2)
                                              const float* __restrict__ Cp,   // (H,M,2)
                                              const float* __restrict__ enc_w,
                                              const float* __restrict__ Wr,
                                              const float* __restrict__ Wt,
                                              const float* __restrict__ Wg,
                                              const float* __restrict__ dtb,
                                              u16* __restrict__ EWhi, u16* __restrict__ EWlo,
                                              u16* __restrict__ HWhi, u16* __restrict__ HWlo, // r, theta
                                              u16* __restrict__ GWhi,
                                              u16* __restrict__ WBh,     // (512,256): Bre rows, Bim rows
                                              u16* __restrict__ Chath,   // (256,512): [h][2m]=Cre,[h][2m+1]=-Cim
                                              float* __restrict__ dtc, float* __restrict__ idt,
                                              float* __restrict__ idt2) {
    int tid = blockIdx.x * 256 + threadIdx.x;  // 0..65535
    if (tid < M_) {
        float d = fmaxf(sigm(dtb[tid]), 1e-6f);
        dtc[tid] = d;
        idt[tid] = 1.0f / d;
        idt2[tid] = 1.0f / (d * d);
    }
    u16 h, l;
    split2(enc_w[tid], h, l); EWhi[tid] = h; EWlo[tid] = l;
    split2(Wr[tid], h, l);    HWhi[tid] = h; HWlo[tid] = l;
    split2(Wt[tid], h, l);    HWhi[65536 + tid] = h; HWlo[65536 + tid] = l;
    GWhi[tid] = f2bf(Wg[tid]);
    WBh[tid]         = f2bf(Bp[2 * tid + 0]);
    WBh[65536 + tid] = f2bf(Bp[2 * tid + 1]);
    int hh = tid >> 8, m = tid & (M_ - 1);
    Chath[hh * 512 + 2 * m + 0] = f2bf(Cp[2 * tid + 0]);
    Chath[hh * 512 + 2 * m + 1] = f2bf(-Cp[2 * tid + 1]);
}

__global__ __launch_bounds__(256) void k_zero(float* __restrict__ p, int n) {
    int i = blockIdx.x * 256 + threadIdx.x;
    if (i < n) p[i] = 0.0f;
}

// ---------------- split-bf16 MFMA GEMM over fp32 A ----------------
// OUT = A(rows,K) @ W[h](256,K)^T per head. NPROD=3: hi*hi+hi*lo+lo*hi; NPROD=1: hi*hi.
// EPI: 1=enc silu+bias (f32 OUT) | 0=heads r,theta -> (A,G) floatx2 NT | 2=gate sigm -> bf16
//      3=bu (NH=2) -> bf16 planes gated by g16, NT
template <int NH, int NPROD, int EPI, bool AGLOB>
__global__ __launch_bounds__(256) void k_sgemm(const float* __restrict__ A,
                                               const u16* __restrict__ Whi,
                                               const u16* __restrict__ Wlo,
                                               void* __restrict__ OUTv,
                                               const u16* __restrict__ g16,
                                               const float* __restrict__ p0,  // bias | rlb
                                               const float* __restrict__ p1,  // tab
                                               const float* __restrict__ p2,  // idt
                                               const float* __restrict__ p3,  // idt2
                                               int K, int C, int t0) {
    constexpr int LOR = (NPROD == 3) ? 128 : 1;
    constexpr int NBL = (NPROD == 3) ? NH : 1;
    __shared__ u16 Ah[128][40];
    __shared__ u16 Al[LOR][40];
    __shared__ u16 Bh[NH][128][40];
    __shared__ u16 Bl[NBL][LOR][40];
    const int tid = threadIdx.x;
    const int tpb = C >> 7;
    const int batch = blockIdx.y / tpb;
    const int i0 = (blockIdx.y % tpb) << 7;
    const int colBase = blockIdx.x << 7;
    const int aRow0 = AGLOB ? (batch * L_ + t0 + i0) : (batch * C + i0);
    const int oRow0 = batch * C + i0;
    const int arow = tid >> 1, aseg = (tid & 1) << 4;
    const float* pa = &A[(size_t)(aRow0 + arow) * K + aseg];
    float4 ra0 = *(const float4*)pa, ra1 = *(const float4*)(pa + 4);
    float4 ra2 = *(const float4*)(pa + 8), ra3 = *(const float4*)(pa + 12);
    const int lane = tid & 63, wv = tid >> 6;
    const int wr = wv >> 1, wc = wv & 1;
    const int fr = lane & 15, kg = lane >> 4;
    floatx4 acc[NH][4][4];
#pragma unroll
    for (int h = 0; h < NH; ++h)
#pragma unroll
        for (int i = 0; i < 4; ++i)
#pragma unroll
            for (int j = 0; j < 4; ++j) acc[h][i][j] = (floatx4){0.f, 0.f, 0.f, 0.f};
    const int KT = K >> 5;
    for (int kt = 0; kt < KT; ++kt) {
        short8v rbh[NH][2], rbl[NBL][2];
#pragma unroll
        for (int h = 0; h < NH; ++h) {
            const u16* pb = &Whi[(size_t)h * 65536 + (size_t)(colBase + arow) * K + kt * 32 + aseg];
            rbh[h][0] = *(const short8v*)pb; rbh[h][1] = *(const short8v*)(pb + 8);
            if (NPROD == 3) {
                const u16* pl = &Wlo[(size_t)h * 65536 + (size_t)(colBase + arow) * K + kt * 32 + aseg];
                rbl[h][0] = *(const short8v*)pl; rbl[h][1] = *(const short8v*)(pl + 8);
            }
        }
        __syncthreads();
        {
            u16 hb[16], lb[16];
            float v[16] = {ra0.x, ra0.y, ra0.z, ra0.w, ra1.x, ra1.y, ra1.z, ra1.w,
                           ra2.x, ra2.y, ra2.z, ra2.w, ra3.x, ra3.y, ra3.z, ra3.w};
#pragma unroll
            for (int s = 0; s < 16; ++s) {
                if (NPROD == 3) split2(v[s], hb[s], lb[s]);
                else hb[s] = f2bf(v[s]);
            }
            *(short8v*)&Ah[arow][aseg] = *(short8v*)&hb[0];
            *(short8v*)&Ah[arow][aseg + 8] = *(short8v*)&hb[8];
            if (NPROD == 3) {
                *(short8v*)&Al[arow][aseg] = *(short8v*)&lb[0];
                *(short8v*)&Al[arow][aseg + 8] = *(short8v*)&lb[8];
            }
        }
#pragma unroll
        for (int h = 0; h < NH; ++h) {
            *(short8v*)&Bh[h][arow][aseg] = rbh[h][0];
            *(short8v*)&Bh[h][arow][aseg + 8] = rbh[h][1];
            if (NPROD == 3) {
                *(short8v*)&Bl[h][arow][aseg] = rbl[h][0];
                *(short8v*)&Bl[h][arow][aseg + 8] = rbl[h][1];
            }
        }
        __syncthreads();
        if (kt + 1 < KT) {
            pa += 32;
            ra0 = *(const float4*)pa; ra1 = *(const float4*)(pa + 4);
            ra2 = *(const float4*)(pa + 8); ra3 = *(const float4*)(pa + 12);
        }
        short8v afh[4], afl[4];
#pragma unroll
        for (int i = 0; i < 4; ++i) afh[i] = *(short8v*)&Ah[wr * 64 + i * 16 + fr][kg << 3];
        if (NPROD == 3) {
#pragma unroll
            for (int i = 0; i < 4; ++i) afl[i] = *(short8v*)&Al[wr * 64 + i * 16 + fr][kg << 3];
        }
#pragma unroll
        for (int h = 0; h < NH; ++h) {
            short8v bfh[4], bfl[4];
#pragma unroll
            for (int j = 0; j < 4; ++j) bfh[j] = *(short8v*)&Bh[h][wc * 64 + j * 16 + fr][kg << 3];
            if (h < NBL && NPROD == 3) {
#pragma unroll
                for (int j = 0; j < 4; ++j) bfl[j] = *(short8v*)&Bl[h][wc * 64 + j * 16 + fr][kg << 3];
            }
#pragma unroll
            for (int i = 0; i < 4; ++i)
#pragma unroll
                for (int j = 0; j < 4; ++j) {
                    floatx4 t = acc[h][i][j];
                    if (NPROD == 3) {
                        t = __builtin_amdgcn_mfma_f32_16x16x32_bf16(afl[i], bfh[j], t, 0, 0, 0);
                        t = __builtin_amdgcn_mfma_f32_16x16x32_bf16(afh[i], bfl[j], t, 0, 0, 0);
                    }
                    t = __builtin_amdgcn_mfma_f32_16x16x32_bf16(afh[i], bfh[j], t, 0, 0, 0);
                    acc[h][i][j] = t;
                }
        }
    }
    // epilogue: D[row=(lane>>4)*4+reg][col=lane&15]
#pragma unroll
    for (int i = 0; i < 4; ++i)
#pragma unroll
        for (int j = 0; j < 4; ++j) {
            int rbase = wr * 64 + i * 16 + (kg << 2);
            int col = colBase + wc * 64 + j * 16 + fr;
#pragma unroll
            for (int r = 0; r < 4; ++r) {
                int orow = oRow0 + rbase + r;
                if (EPI == 1) {
                    float v = acc[0][i][j][r] + p0[col];
                    ((float*)OUTv)[(size_t)orow * 256 + col] = v * sigm(v);
                } else if (EPI == 2) {
                    ((u16*)OUTv)[(size_t)orow * 256 + col] = f2bf(sigm(acc[0][i][j][r]));
                } else if (EPI == 0) {
                    float rr = sigm(p0[col] + acc[0][i][j][r]);
                    float th = PI_F * tanhf(p1[col] + acc[1][i][j][r]);
                    float r2 = fmaxf(rr * rr, 1e-8f);
                    float Av = fmaxf((r2 - 2.0f * rr * cosf(th) + 1.0f) * p3[col] / r2, 0.0f);
                    float Gv = fmaxf((1.0f - r2) * p2[col] / r2, 0.0f);
                    floatx2 o = (floatx2){Av, Gv};
                    __builtin_nontemporal_store(o, (floatx2*)&((float*)OUTv)[((size_t)orow * 256 + col) * 2]);
                } else {  // EPI==3: bu, NH=2 planes, gated, NT store
                    float g = bf2f(g16[(size_t)orow * 256 + col]);
#pragma unroll
                    for (int h = 0; h < NH; ++h)
                        __builtin_nontemporal_store(f2bf(acc[h][i][j][r] * g),
                                                    &((u16*)OUTv)[(size_t)orow * 512 + h * 256 + col]);
                }
            }
        }
}

// ---------------- depthwise causal conv (K=4) + SiLU ----------------
__global__ __launch_bounds__(256) void k_conv(const float* __restrict__ F0,   // (B*C,H)
                                              const float* __restrict__ TAIL, // (B,3,H)
                                              const float* __restrict__ cw,
                                              const float* __restrict__ cb,
                                              float* __restrict__ F,
                                              int t0, int C) {
    int idx = blockIdx.x * 256 + threadIdx.x;
    int h = idx & (H_ - 1);
    int rl = idx >> 8;
    int b = rl / C;
    int dtl = rl - b * C;
    int t = t0 + dtl;
    float w0 = cw[h * 4 + 0], w1 = cw[h * 4 + 1], w2 = cw[h * 4 + 2], w3 = cw[h * 4 + 3];
    float acc = cb[h];
    acc = fmaf(F0[(size_t)rl * H_ + h], w3, acc);
#pragma unroll
    for (int kk = 1; kk <= 3; ++kk) {
        float w = (kk == 1) ? w2 : (kk == 2) ? w1 : w0;
        if (t - kk >= 0) {
            float src;
            if (dtl - kk >= 0) src = F0[(size_t)(rl - kk) * H_ + h];
            else               src = TAIL[((b * 3 + (3 + dtl - kk)) << 8) + h];
            acc = fmaf(src, w, acc);
        }
    }
    F[(size_t)rl * H_ + h] = acc * sigm(acc);
}

__global__ __launch_bounds__(256) void k_tail(const float* __restrict__ F0,
                                              float* __restrict__ TAIL, int C) {
    int b = blockIdx.x / 3, j = blockIdx.x % 3, h = threadIdx.x;
    TAIL[((b * 3 + j) << 8) + h] = F0[((size_t)(b * C + C - 3 + j) << 8) + h];
}

// ---------------- parallel scan pass 1 ----------------
#define SEG_ 64
__global__ __launch_bounds__(256) void k_scan1(const float* __restrict__ AGf2,
                                               const u16* __restrict__ BUh,
                                               const float* __restrict__ dtc_,
                                               float* __restrict__ SEGM,
                                               float* __restrict__ SEGV,
                                               int C) {
    int m = threadIdx.x;
    int nseg = C >> 6;
    int b = blockIdx.x / nseg;
    int s = blockIdx.x - b * nseg;
    float dt = dtc_[m];
    size_t row0 = (size_t)b * C + s * SEG_;
    float a = 1.f, bb = 0.f, c = 0.f, d = 1.f;
    float vzr = 0.f, vzi = 0.f, vxr = 0.f, vxi = 0.f;
    for (int t = 0; t < SEG_; ++t) {
        size_t row = row0 + t;
        float2 ag = *(const float2*)&AGf2[(row * 256 + m) * 2];
        float br = bf2f(BUh[row * 512 + m]);
        float bi = bf2f(BUh[row * 512 + 256 + m]);
        float S = fmaf(dt, ag.y, 1.0f);
        float e = 1.0f / fmaxf(S, 1e-6f);
        float sa = e;
        float sb = -dt * ag.x * e;
        float sc = dt * e;
        float sd = fmaf(dt, sb, 1.0f);
        float na = fmaf(sa, a, sb * c), nb = fmaf(sa, bb, sb * d);
        float nc = fmaf(sc, a, sd * c), nd = fmaf(sc, bb, sd * d);
        float wz = dt * e;
        float nvzr = fmaf(sa, vzr, fmaf(sb, vxr, wz * br));
        float nvzi = fmaf(sa, vzi, fmaf(sb, vxi, wz * bi));
        float nvxr = fmaf(sc, vzr, fmaf(sd, vxr, dt * wz * br));
        float nvxi = fmaf(sc, vzi, fmaf(sd, vxi, dt * wz * bi));
        a = na; bb = nb; c = nc; d = nd;
        vzr = nvzr; vzi = nvzi; vxr = nvxr; vxi = nvxi;
    }
    size_t o = ((size_t)blockIdx.x * M_ + m) * 4;
    *(float4*)&SEGM[o] = make_float4(a, bb, c, d);
    *(float4*)&SEGV[o] = make_float4(vzr, vzi, vxr, vxi);
}

// ---------------- scan pass 2 ----------------
__global__ __launch_bounds__(256) void k_scan2(const float* __restrict__ SEGM,
                                               const float* __restrict__ SEGV,
                                               float* __restrict__ carry,
                                               float* __restrict__ PRE,
                                               int C) {
    int m = threadIdx.x;
    int b = blockIdx.x;
    int nseg = C >> 6;
    float4 st = *(float4*)&carry[(size_t)(b * M_ + m) * 4];
    for (int s = 0; s < nseg; ++s) {
        size_t o = ((size_t)(b * nseg + s) * M_ + m) * 4;
        *(float4*)&PRE[o] = st;
        float4 Mm = *(const float4*)&SEGM[o];
        float4 Vv = *(const float4*)&SEGV[o];
        float nzr = fmaf(Mm.x, st.x, fmaf(Mm.y, st.z, Vv.x));
        float nzi = fmaf(Mm.x, st.y, fmaf(Mm.y, st.w, Vv.y));
        float nxr = fmaf(Mm.z, st.x, fmaf(Mm.w, st.z, Vv.z));
        float nxi = fmaf(Mm.z, st.y, fmaf(Mm.w, st.w, Vv.w));
        st = make_float4(nzr, nzi, nxr, nxi);
    }
    *(float4*)&carry[(size_t)(b * M_ + m) * 4] = st;
}

// ---------------- scan pass 3 fused with projection GEMM + D*x residual ----------------
__global__ __launch_bounds__(256) void k_scan3p(const float* __restrict__ AGf2,
                                                const u16* __restrict__ BUh,
                                                const float* __restrict__ dtc_,
                                                const float* __restrict__ PRE,
                                                const u16* __restrict__ Chath,  // (256,512)
                                                const float* __restrict__ Dv,
                                                const float* __restrict__ X0,   // inputs (global rows)
                                                float* __restrict__ OUT,        // (global rows)
                                                int t0, int C) {
    __shared__ u16 XT[32][520];
    __shared__ u16 Bs[256][40];
    const int tid = threadIdx.x;
    const int m = tid;
    const int nseg = C >> 6;
    const int b = blockIdx.x / nseg;
    const int s = blockIdx.x - b * nseg;
    const float dt = dtc_[m];
    float4 st = *(const float4*)&PRE[((size_t)blockIdx.x * M_ + m) * 4];
    float zr = st.x, zi = st.y, xr = st.z, xi = st.w;
    const size_t row0 = (size_t)b * C + s * SEG_;
    const int grow0 = b * L_ + t0 + s * SEG_;
    const int lane = tid & 63, wc = tid >> 6;
    const int fr = lane & 15, kg = lane >> 4;
#pragma unroll
    for (int half = 0; half < 2; ++half) {
        for (int t = 0; t < 32; ++t) {
            size_t row = row0 + half * 32 + t;
            floatx2 ag = __builtin_nontemporal_load((const floatx2*)&AGf2[(row * 256 + m) * 2]);
            float br = bf2f(__builtin_nontemporal_load(&BUh[row * 512 + m]));
            float bi = bf2f(__builtin_nontemporal_load(&BUh[row * 512 + 256 + m]));
            float S = fmaf(dt, ag[1], 1.0f);
            float inv = 1.0f / fmaxf(S, 1e-6f);
            zr = fmaf(dt, fmaf(-ag[0], xr, br), zr) * inv;
            zi = fmaf(dt, fmaf(-ag[0], xi, bi), zi) * inv;
            xr = fmaf(dt, zr, xr);
            xi = fmaf(dt, zi, xi);
            unsigned int pk = (unsigned int)f2bf(xr) | ((unsigned int)f2bf(xi) << 16);
            *(unsigned int*)&XT[t][2 * m] = pk;
        }
        __syncthreads();
        floatx4 pacc[2][4];
#pragma unroll
        for (int i = 0; i < 2; ++i)
#pragma unroll
            for (int j = 0; j < 4; ++j) pacc[i][j] = (floatx4){0.f, 0.f, 0.f, 0.f};
        for (int kc = 0; kc < 16; ++kc) {
            const u16* pc = &Chath[(size_t)tid * 512 + kc * 32];
            short8v c0 = *(const short8v*)pc;
            short8v c1 = *(const short8v*)(pc + 8);
            short8v c2 = *(const short8v*)(pc + 16);
            short8v c3 = *(const short8v*)(pc + 24);
            *(short8v*)&Bs[tid][0]  = c0;
            *(short8v*)&Bs[tid][8]  = c1;
            *(short8v*)&Bs[tid][16] = c2;
            *(short8v*)&Bs[tid][24] = c3;
            __syncthreads();
            short8v af[2], bf[4];
#pragma unroll
            for (int i = 0; i < 2; ++i) af[i] = *(short8v*)&XT[i * 16 + fr][kc * 32 + (kg << 3)];
#pragma unroll
            for (int j = 0; j < 4; ++j) bf[j] = *(short8v*)&Bs[wc * 64 + j * 16 + fr][kg << 3];
#pragma unroll
            for (int i = 0; i < 2; ++i)
#pragma unroll
                for (int j = 0; j < 4; ++j)
                    pacc[i][j] = __builtin_amdgcn_mfma_f32_16x16x32_bf16(af[i], bf[j], pacc[i][j], 0, 0, 0);
            __syncthreads();
        }
#pragma unroll
        for (int i = 0; i < 2; ++i)
#pragma unroll
            for (int j = 0; j < 4; ++j) {
                int col = wc * 64 + j * 16 + fr;
#pragma unroll
                for (int r = 0; r < 4; ++r) {
                    int grow = grow0 + half * 32 + i * 16 + (kg << 2) + r;
                    float x0 = __builtin_nontemporal_load(&X0[(size_t)grow * 256 + col]);
                    __builtin_nontemporal_store(fmaf(Dv[col], x0, pacc[i][j][r]),
                                                &OUT[(size_t)grow * 256 + col]);
                }
            }
        __syncthreads();
    }
}

extern "C" void kernel_launch(void* const* d_in, const int* in_sizes, int n_in,
                              void* d_out, int out_size, void* d_ws, size_t ws_size,
                              hipStream_t stream) {
    const float* inputs = (const float*)d_in[0];
    const float* Bp     = (const float*)d_in[1];
    const float* Cp     = (const float*)d_in[2];
    const float* Dv     = (const float*)d_in[3];
    const float* enc_w  = (const float*)d_in[4];
    const float* enc_b  = (const float*)d_in[5];
    const float* conv_w = (const float*)d_in[6];
    const float* conv_b = (const float*)d_in[7];
    const float* rlb    = (const float*)d_in[8];
    const float* tab    = (const float*)d_in[9];
    const float* Wr     = (const float*)d_in[10];
    const float* Wt     = (const float*)d_in[11];
    const float* dtb    = (const float*)d_in[12];
    const float* Wg     = (const float*)d_in[13];

    // C=4096 preferred (round 9 showed chunking smaller hurts); shrink only if ws too small
    int C = 4096;
    while (C > 128) {
        size_t need = (size_t)B_ * C * 5632 + (48ull << 20);
        if (need <= ws_size) break;
        C >>= 1;
    }

    char* ws = (char*)d_ws;
    size_t off = 0;
    auto alloc = [&](size_t bytes) -> char* {
        char* p = ws + off;
        off = (off + bytes + 1023) & ~(size_t)1023;
        return p;
    };
    const int rows = B_ * C;
    const int nseg = C >> 6;
    float* F0   = (float*)alloc((size_t)rows * 256 * 4);
    float* F    = (float*)alloc((size_t)rows * 256 * 4);
    float* AGf2 = (float*)alloc((size_t)rows * 512 * 4);
    u16*   GTh  = (u16*)alloc((size_t)rows * 256 * 2);
    u16*   BUh  = (u16*)alloc((size_t)rows * 512 * 2);
    float* SEGM = (float*)alloc((size_t)B_ * nseg * M_ * 16);
    float* SEGV = (float*)alloc((size_t)B_ * nseg * M_ * 16);
    float* PRE  = (float*)alloc((size_t)B_ * nseg * M_ * 16);
    u16* EWhi = (u16*)alloc(65536 * 2);
    u16* EWlo = (u16*)alloc(65536 * 2);
    u16* HWhi = (u16*)alloc(2 * 65536 * 2);
    u16* HWlo = (u16*)alloc(2 * 65536 * 2);
    u16* GWhi = (u16*)alloc(65536 * 2);
    u16* WBh  = (u16*)alloc(2 * 65536 * 2);
    u16* Chath= (u16*)alloc(2 * 65536 * 2);
    float* dtc  = (float*)alloc(1024);
    float* idt  = (float*)alloc(1024);
    float* idt2 = (float*)alloc(1024);
    float* carry= (float*)alloc(B_ * M_ * 16);
    float* TAIL = (float*)alloc(B_ * 3 * 256 * 4);

    const int NC = L_ / C;
    const int tpb = C >> 7;

    k_prep<<<256, 256, 0, stream>>>(Bp, Cp, enc_w, Wr, Wt, Wg, dtb,
                                    EWhi, EWlo, HWhi, HWlo, GWhi, WBh, Chath, dtc, idt, idt2);
    k_zero<<<(B_ * M_ * 4 + 255) / 256, 256, 0, stream>>>(carry, B_ * M_ * 4);

    for (int c = 0; c < NC; ++c) {
        int t0 = c * C;
        // encoder: split-bf16, silu(x@EW^T+b) -> F0
        k_sgemm<1, 3, 1, true><<<dim3(2, B_ * tpb), 256, 0, stream>>>(
            inputs, EWhi, EWlo, F0, nullptr, enc_b, nullptr, nullptr, nullptr, 256, C, t0);
        k_conv<<<rows, 256, 0, stream>>>(F0, TAIL, conv_w, conv_b, F, t0, C);
        if (NC > 1) k_tail<<<B_ * 3, 256, 0, stream>>>(F0, TAIL, C);
        // r/theta heads: split-bf16 -> (A,G) floatx2 (NT store)
        k_sgemm<2, 3, 0, false><<<dim3(2, B_ * tpb), 256, 0, stream>>>(
            F, HWhi, HWlo, AGf2, nullptr, rlb, tab, idt, idt2, 256, C, t0);
        // gate head: plain bf16 -> sigm -> bf16 GTh
        k_sgemm<1, 1, 2, false><<<dim3(2, B_ * tpb), 256, 0, stream>>>(
            F, GWhi, nullptr, GTh, nullptr, nullptr, nullptr, nullptr, nullptr, 256, C, t0);
        // bu: two heads (re,im) from fp32 inputs, gated -> bf16 BUh (NT store)
        k_sgemm<2, 1, 3, true><<<dim3(2, B_ * tpb), 256, 0, stream>>>(
            inputs, WBh, nullptr, BUh, GTh, nullptr, nullptr, nullptr, nullptr, 256, C, t0);
        k_scan1<<<B_ * nseg, 256, 0, stream>>>(AGf2, BUh, dtc, SEGM, SEGV, C);
        k_scan2<<<B_, 256, 0, stream>>>(SEGM, SEGV, carry, PRE, C);
        k_scan3p<<<B_ * nseg, 256, 0, stream>>>(AGf2, BUh, dtc, PRE, Chath, Dv, inputs,
                                                (float*)d_out, t0, C);
    }
}